// Round 7
// baseline (210.738 us; speedup 1.0000x reference)
//
#include <hip/hip_runtime.h>

// MemoryEfficientAttention: x->(Q,K,V) proj (bf16 MFMA, scale*log2e folded into Q),
// chunked-mask flash attention (double-swapped MFMA, exp2-domain lane-local softmax,
// counted-vmcnt 3-deep pipeline, paired q-tiles for uniform block length),
// O-proj (split-A bf16x2 MFMA, 64x64 tile). fp32 in/out.
// Mask: past blocks masked, diagonal block causal, future blocks visible.

typedef __attribute__((ext_vector_type(8))) short bf16x8;
typedef __attribute__((ext_vector_type(4))) float f32x4;
typedef __attribute__((ext_vector_type(4))) float float4v;
typedef __attribute__((ext_vector_type(4))) unsigned short u16x4;

__device__ __forceinline__ unsigned short f2bf(float x){
  union { float f; unsigned int u; } c; c.f = x;
  unsigned int r = c.u + 0x7FFFu + ((c.u >> 16) & 1u);
  return (unsigned short)(r >> 16);
}
__device__ __forceinline__ float bf2f(unsigned short h){
  union { unsigned int u; float f; } c; c.u = ((unsigned int)h) << 16;
  return c.f;
}
__device__ __forceinline__ f32x4 zero4(){ f32x4 v; v[0]=0.f; v[1]=0.f; v[2]=0.f; v[3]=0.f; return v; }
__device__ __forceinline__ unsigned int cvtpk(float a, float b){
  unsigned int r;
  asm("v_cvt_pk_bf16_f32 %0, %1, %2" : "=v"(r) : "v"(a), "v"(b));
  return r;
}
__device__ __forceinline__ float exp2x(float x){   // raw v_exp_f32 = 2^x
  float r;
  asm("v_exp_f32 %0, %1" : "=v"(r) : "v"(x));
  return r;
}
// counted-vmcnt barrier (T4): allow the n newest loads to stay in flight.
// vmcnt decrements in issue order => all older loads are complete after this.
__device__ __forceinline__ void wait_barrier(int n){
  if (n == 4)      asm volatile("s_waitcnt vmcnt(4)" ::: "memory");
  else if (n == 2) asm volatile("s_waitcnt vmcnt(2)" ::: "memory");
  else             asm volatile("s_waitcnt vmcnt(0)" ::: "memory");
  __builtin_amdgcn_s_barrier();
  __builtin_amdgcn_sched_barrier(0);
}

// async global->LDS, 16B per lane; LDS dest wave-uniform, global src per-lane
#define GLDS16(g, l) __builtin_amdgcn_global_load_lds( \
  (const __attribute__((address_space(1))) void*)(g), \
  (__attribute__((address_space(3))) void*)(l), 16, 0, 0)

// ---------------- prep: cast x and all weights to bf16, gather biases ----------------
__global__ __launch_bounds__(256) void k_prep(
    const float* __restrict__ x,
    const float* __restrict__ Wq, const float* __restrict__ Wk,
    const float* __restrict__ Wv, const float* __restrict__ Wo,
    const float* __restrict__ bq, const float* __restrict__ bk, const float* __restrict__ bv,
    unsigned short* __restrict__ xh, unsigned short* __restrict__ wh,
    float* __restrict__ bias_cat){
  const int NX = 1048576;                     // x float4 count (4096*1024/4)
  const int NTOT = 2097152;                   // + 4 weight matrices
  int i = blockIdx.x * 256 + threadIdx.x;
  if (i < 3072){
    const float* bs[3] = {bq, bk, bv};
    bias_cat[i] = bs[i >> 10][i & 1023];
  }
  int stride = gridDim.x * 256;
  for (; i < NTOT; i += stride){
    float4v v;
    u16x4 h;
    if (i < NX){
      v = ((const float4v*)x)[i];
      #pragma unroll
      for (int j = 0; j < 4; ++j) h[j] = f2bf(v[j]);
      ((u16x4*)xh)[i] = h;
    } else {
      int jj = i - NX;
      const float* srcs[4] = {Wq, Wk, Wv, Wo};
      v = ((const float4v*)srcs[jj >> 18])[jj & 0x3FFFF];
      #pragma unroll
      for (int j = 0; j < 4; ++j) h[j] = f2bf(v[j]);
      ((u16x4*)wh)[jj] = h;
    }
  }
}

// ---------------- GEMM: out = A @ W^T + bias ----------------
// MODE 0: N=3072 fused QKV -> scatter Q[b,h,t,d]*scale*log2e, K[b,h,t,d], Vt[b,h,d,t]
// MODE 1: N=1024 -> fp32 out + bias
template<int BM, int BN, int MODE, int SPLITA>
__global__ __launch_bounds__(256) void k_gemm(
    const unsigned short* __restrict__ Ah, const unsigned short* __restrict__ Al,
    const unsigned short* __restrict__ Bh,
    const float* __restrict__ bias, const float* __restrict__ scale_p,
    unsigned short* __restrict__ oq, unsigned short* __restrict__ okk,
    unsigned short* __restrict__ ov, float* __restrict__ fo)
{
  constexpr int MF = (BN == 128) ? (BM/32) : (BM/64);
  constexpr int NF = 4;
  constexpr int AISS = BM/64;
  constexpr int BISS = BN/64;
  constexpr int NA = SPLITA ? 2 : 1;
  __shared__ unsigned short As[NA][BM*32];
  __shared__ unsigned short Bs[BN*32];

  const int tid  = threadIdx.x;
  const int wid  = tid >> 6;
  const int lane = tid & 63;
  const int l15  = lane & 15;
  const int kg   = lane >> 4;
  const int m0 = blockIdx.y * BM;
  const int n0 = blockIdx.x * BN;
  const int wrb = (BN == 128) ? (wid >> 1) * (BM/2) : wid * (BM/4);
  const int wcb = (BN == 128) ? (wid & 1) * 64 : 0;
  const float qs = (MODE == 0) ? scale_p[0] * 1.4426950408889634f : 0.f;  // fold log2e

  f32x4 acc[MF][NF];
  #pragma unroll
  for (int a = 0; a < MF; ++a)
    #pragma unroll
    for (int b = 0; b < NF; ++b) acc[a][b] = zero4();

  for (int k0 = 0; k0 < 1024; k0 += 32){
    #pragma unroll
    for (int p = 0; p < NA; ++p){
      const unsigned short* Asrc = p ? Al : Ah;
      #pragma unroll
      for (int iss = 0; iss < AISS; ++iss){
        int L = iss*2048 + tid*8;
        int row = L >> 5;
        int ck = ((L >> 3) & 3) ^ ((row >> 1) & 3);
        GLDS16(Asrc + (size_t)(m0 + row)*1024 + k0 + ck*8,
               (char*)(&As[p][0]) + iss*4096 + wid*1024);
      }
    }
    #pragma unroll
    for (int iss = 0; iss < BISS; ++iss){
      int L = iss*2048 + tid*8;
      int row = L >> 5;
      int ck = ((L >> 3) & 3) ^ ((row >> 1) & 3);
      GLDS16(Bh + (size_t)(n0 + row)*1024 + k0 + ck*8,
             (char*)(&Bs[0]) + iss*4096 + wid*1024);
    }
    __syncthreads();

    bf16x8 af[MF][NA];
    #pragma unroll
    for (int mf = 0; mf < MF; ++mf){
      int r = wrb + mf*16 + l15;
      int ckpos = kg ^ ((r >> 1) & 3);
      #pragma unroll
      for (int p = 0; p < NA; ++p)
        af[mf][p] = *(const bf16x8*)((const char*)(&As[p][0]) + r*64 + ckpos*16);
    }
    #pragma unroll
    for (int nf = 0; nf < NF; ++nf){
      int r = wcb + nf*16 + l15;
      int ckpos = kg ^ ((r >> 1) & 3);
      bf16x8 bhv = *(const bf16x8*)((const char*)(&Bs[0]) + r*64 + ckpos*16);
      #pragma unroll
      for (int mf = 0; mf < MF; ++mf){
        acc[mf][nf] = __builtin_amdgcn_mfma_f32_16x16x32_bf16(af[mf][0], bhv, acc[mf][nf], 0,0,0);
        if (SPLITA)
          acc[mf][nf] = __builtin_amdgcn_mfma_f32_16x16x32_bf16(af[mf][1], bhv, acc[mf][nf], 0,0,0);
      }
    }
    __syncthreads();
  }

  #pragma unroll
  for (int mf = 0; mf < MF; ++mf){
    #pragma unroll
    for (int nf = 0; nf < NF; ++nf){
      int colg = n0 + wcb + nf*16 + l15;
      float bb = bias[colg];
      #pragma unroll
      for (int j = 0; j < 4; ++j){
        int r = m0 + wrb + mf*16 + kg*4 + j;
        float val = acc[mf][nf][j] + bb;
        if (MODE == 1){
          fo[(size_t)r*1024 + colg] = val;
        } else {
          int bi = r >> 11, tt = r & 2047;
          int mat = colg >> 10, jj = colg & 1023;
          int h = jj >> 6, d = jj & 63;
          size_t bh_ = (size_t)(bi*16 + h);
          if (mat == 0)      oq [(bh_*2048 + tt)*64 + d] = f2bf(val * qs);
          else if (mat == 1) okk[(bh_*2048 + tt)*64 + d] = f2bf(val);
          else               ov [(bh_*64 + d)*2048 + tt] = f2bf(val);  // V^T
        }
      }
    }
  }
}

// ---------------- flash attention, counted-vmcnt pipelined ----------------
// grid: 512 = pair(16) x bh(32); block does q-tiles {p, 31-p} = 33 KV-tiles uniform.
// ST = mfma(K,Q): col=l15=q, row=kg*4+j=k.  Ot = mfma(V^T,P^T): col=l15=q, row=d.
// Pipeline: iter t issues K[t+3],V[t+2]; computes QK(t+1) [MFMA] overlapped with
// softmax(t) [VALU]; ends with s_waitcnt vmcnt(#issued) + raw s_barrier (T3/T4).
// Qs LDS doubles as per-wave P tile after the one-time Q-fragment load.
__global__ __launch_bounds__(256) void k_attn(
    const unsigned short* __restrict__ Qg, const unsigned short* __restrict__ Kg,
    const unsigned short* __restrict__ Vtg,
    unsigned short* __restrict__ Ohi, unsigned short* __restrict__ Olo)
{
  __shared__ unsigned short Qs[4096];        // Q tile -> P tiles
  __shared__ unsigned short Ks[3][4096];     // 3-deep K ring
  __shared__ unsigned short Vts[3][4096];    // 3-deep V^T ring (rows=d, cols=kv)

  const int tid  = threadIdx.x;
  const int wid  = tid >> 6;
  const int lane = tid & 63;
  const int l15  = lane & 15;
  const int kg   = lane >> 4;
  const int pr = blockIdx.x >> 5;            // pair 0..15
  const int bh = blockIdx.x & 31;
  const size_t base = (size_t)bh * (2048*64);

  const int r0 = tid >> 3;                   // staging row (iss1 = r0+32)
  const int ck = ((tid & 7) ^ (r0 & 7)) * 8; // swizzled chunk
  const int c0 = (kg ^ (l15 & 7)) << 4;
  const int c1 = c0 ^ 64;
  const char* qbase = (const char*)Qs + wid*2048 + l15*128;   // qf slice == P slice
  char* pwb = (char*)Qs + wid*2048 + l15*128;
  const int pws = (kg*8) ^ ((l15 & 7) << 4);
  const int qloc = wid*16 + l15;
  const int bi = bh >> 4, h = bh & 15;

  #pragma unroll 1
  for (int half = 0; half < 2; ++half){
    const int t0 = half ? (31 - pr) : pr;
    // ---- prologue: Q, K[t0], V[t0], K[t0+1] ----
    const unsigned short* qp  = Qg  + base + (size_t)(t0*64 + r0)*64 + ck;
    const unsigned short* kp0 = Kg  + base + (size_t)(t0*64 + r0)*64 + ck;
    const unsigned short* vp0 = Vtg + base + (size_t)r0*2048 + t0*64 + ck;
    GLDS16(qp,          (char*)Qs + wid*1024);
    GLDS16(qp + 2048,   (char*)Qs + wid*1024 + 4096);
    GLDS16(kp0,         (char*)(&Ks[0][0]) + wid*1024);
    GLDS16(kp0 + 2048,  (char*)(&Ks[0][0]) + wid*1024 + 4096);
    GLDS16(vp0,         (char*)(&Vts[0][0]) + wid*1024);
    GLDS16(vp0 + 65536, (char*)(&Vts[0][0]) + wid*1024 + 4096);
    int nA = 0;
    if (t0 + 1 <= 31){
      GLDS16(kp0 + 4096, (char*)(&Ks[1][0]) + wid*1024);
      GLDS16(kp0 + 6144, (char*)(&Ks[1][0]) + wid*1024 + 4096);
      nA = 2;
    }
    wait_barrier(nA);               // Q, K[t0], V[t0] resident

    const bf16x8 qf0 = *(const bf16x8*)(qbase + c0);
    const bf16x8 qf1 = *(const bf16x8*)(qbase + c1);

    // ST = QK(t0) + diagonal causal mask
    f32x4 ST[4];
    #pragma unroll
    for (int nf = 0; nf < 4; ++nf) ST[nf] = zero4();
    {
      const char* ksb = (const char*)(&Ks[0][0]) + l15*128;
      __builtin_amdgcn_s_setprio(1);
      #pragma unroll
      for (int nf = 0; nf < 4; ++nf){
        bf16x8 ak = *(const bf16x8*)(ksb + nf*2048 + c0);
        ST[nf] = __builtin_amdgcn_mfma_f32_16x16x32_bf16(ak, qf0, ST[nf], 0,0,0);
      }
      #pragma unroll
      for (int nf = 0; nf < 4; ++nf){
        bf16x8 ak = *(const bf16x8*)(ksb + nf*2048 + c1);
        ST[nf] = __builtin_amdgcn_mfma_f32_16x16x32_bf16(ak, qf1, ST[nf], 0,0,0);
      }
      __builtin_amdgcn_s_setprio(0);
    }
    #pragma unroll
    for (int nf = 0; nf < 4; ++nf)
      #pragma unroll
      for (int j = 0; j < 4; ++j)
        if (nf*16 + kg*4 + j > qloc) ST[nf][j] = -1e30f;

    // group B: V[t0+1], K[t0+2]
    int nB = 0;
    if (t0 + 1 <= 31){
      GLDS16(vp0 + 64,         (char*)(&Vts[1][0]) + wid*1024);
      GLDS16(vp0 + 64 + 65536, (char*)(&Vts[1][0]) + wid*1024 + 4096);
      nB += 2;
    }
    if (t0 + 2 <= 31){
      GLDS16(kp0 + 8192,  (char*)(&Ks[2][0]) + wid*1024);
      GLDS16(kp0 + 10240, (char*)(&Ks[2][0]) + wid*1024 + 4096);
      nB += 2;
    }
    wait_barrier(nB);               // K[t0+1] resident

    f32x4 Ot[4];
    #pragma unroll
    for (int d = 0; d < 4; ++d) Ot[d] = zero4();
    float m = -1e30f, l = 0.f;
    const unsigned short* kp = kp0 + 12288;   // K[t0+3]
    const unsigned short* vp = vp0 + 128;     // V[t0+2]
    int s0 = 0, s1 = 1, s2 = 2;               // ring slots: K[kb]=s0,K[kb+1]=s1,K[kb+2]=s2 (V same)

    for (int kb = t0; kb < 32; ++kb){
      // 1. issue prefetch: K[kb+3]->Ks[s0], V[kb+2]->Vts[s2]
      int nIss = 0;
      if (kb + 3 <= 31){
        char* dK = (char*)(&Ks[s0][0]) + wid*1024;
        GLDS16(kp, dK);
        GLDS16(kp + 2048, dK + 4096);
        kp += 4096; nIss += 2;
      }
      if (kb + 2 <= 31){
        char* dV = (char*)(&Vts[s2][0]) + wid*1024;
        GLDS16(vp, dV);
        GLDS16(vp + 65536, dV + 4096);
        vp += 64; nIss += 2;
      }
      // 2. QK(kb+1) -> STn (MFMA pipe; independent of softmax(kb))
      f32x4 STn[4];
      if (kb < 31){
        const char* ksb = (const char*)(&Ks[s1][0]) + l15*128;
        #pragma unroll
        for (int nf = 0; nf < 4; ++nf) STn[nf] = zero4();
        __builtin_amdgcn_s_setprio(1);
        #pragma unroll
        for (int nf = 0; nf < 4; ++nf){
          bf16x8 ak = *(const bf16x8*)(ksb + nf*2048 + c0);
          STn[nf] = __builtin_amdgcn_mfma_f32_16x16x32_bf16(ak, qf0, STn[nf], 0,0,0);
        }
        #pragma unroll
        for (int nf = 0; nf < 4; ++nf){
          bf16x8 ak = *(const bf16x8*)(ksb + nf*2048 + c1);
          STn[nf] = __builtin_amdgcn_mfma_f32_16x16x32_bf16(ak, qf1, STn[nf], 0,0,0);
        }
        __builtin_amdgcn_s_setprio(0);
      }
      // 3. softmax(kb) on ST (VALU pipe, exp2 domain)
      float mx0 = fmaxf(fmaxf(ST[0][0], ST[0][1]), fmaxf(ST[0][2], ST[0][3]));
      float mx1 = fmaxf(fmaxf(ST[1][0], ST[1][1]), fmaxf(ST[1][2], ST[1][3]));
      float mx2 = fmaxf(fmaxf(ST[2][0], ST[2][1]), fmaxf(ST[2][2], ST[2][3]));
      float mx3 = fmaxf(fmaxf(ST[3][0], ST[3][1]), fmaxf(ST[3][2], ST[3][3]));
      float pmax = fmaxf(fmaxf(mx0, mx1), fmaxf(mx2, mx3));
      pmax = fmaxf(pmax, __shfl_xor(pmax, 16, 64));
      pmax = fmaxf(pmax, __shfl_xor(pmax, 32, 64));
      if (!__all(pmax <= m + 8.0f)){    // defer-max (T13): P bounded by 2^8
        float mn = fmaxf(m, pmax);
        float fj = exp2x(m - mn);
        m = mn;
        l *= fj;
        #pragma unroll
        for (int df = 0; df < 4; ++df)
          #pragma unroll
          for (int j = 0; j < 4; ++j) Ot[df][j] *= fj;
      }
      float rsn[4];
      unsigned int pk[4][2];
      #pragma unroll
      for (int nf = 0; nf < 4; ++nf){
        float p0 = exp2x(ST[nf][0] - m), p1 = exp2x(ST[nf][1] - m);
        float p2 = exp2x(ST[nf][2] - m), p3 = exp2x(ST[nf][3] - m);
        rsn[nf] = (p0 + p1) + (p2 + p3);
        pk[nf][0] = cvtpk(p0, p1);
        pk[nf][1] = cvtpk(p2, p3);
      }
      float rs = (rsn[0] + rsn[1]) + (rsn[2] + rsn[3]);
      rs += __shfl_xor(rs, 16, 64);
      rs += __shfl_xor(rs, 32, 64);
      l += rs;
      // 4. P -> wave-private LDS slice, then PV(kb) from Vts[s0]
      #pragma unroll
      for (int nf = 0; nf < 4; ++nf)
        *(uint2*)(pwb + (pws ^ (nf*32))) = make_uint2(pk[nf][0], pk[nf][1]);
      {
        bf16x8 pa0 = *(const bf16x8*)(qbase + c0);
        bf16x8 pa1 = *(const bf16x8*)(qbase + c1);
        const char* vsb = (const char*)(&Vts[s0][0]) + l15*128;
        __builtin_amdgcn_s_setprio(1);
        #pragma unroll
        for (int df = 0; df < 4; ++df){
          bf16x8 vb = *(const bf16x8*)(vsb + df*2048 + c0);
          Ot[df] = __builtin_amdgcn_mfma_f32_16x16x32_bf16(vb, pa0, Ot[df], 0,0,0);
        }
        #pragma unroll
        for (int df = 0; df < 4; ++df){
          bf16x8 vb = *(const bf16x8*)(vsb + df*2048 + c1);
          Ot[df] = __builtin_amdgcn_mfma_f32_16x16x32_bf16(vb, pa1, Ot[df], 0,0,0);
        }
        __builtin_amdgcn_s_setprio(0);
      }
      // 5. rotate pipeline state
      if (kb < 31){
        #pragma unroll
        for (int nf = 0; nf < 4; ++nf) ST[nf] = STn[nf];
      }
      int tmp = s0; s0 = s1; s1 = s2; s2 = tmp;
      // 6. counted-vmcnt barrier: only THIS iter's loads may remain in flight
      wait_barrier(nIss);
    }

    // epilogue: O /= l (lane-local), hi/lo split, 8B vector stores
    const float rinv = 1.0f / l;
    const size_t row = (size_t)(bi*2048 + t0*64 + qloc);
    #pragma unroll
    for (int df = 0; df < 4; ++df){
      int colb = h*64 + df*16 + kg*4;
      u16x4 hv, lv;
      #pragma unroll
      for (int j = 0; j < 4; ++j){
        float v = Ot[df][j] * rinv;
        unsigned short hvv = f2bf(v);
        hv[j] = hvv;
        lv[j] = f2bf(v - bf2f(hvv));
      }
      *(u16x4*)(Ohi + row*1024 + colb) = hv;
      *(u16x4*)(Olo + row*1024 + colb) = lv;
    }
  }
}

extern "C" void kernel_launch(void* const* d_in, const int* in_sizes, int n_in,
                              void* d_out, int out_size, void* d_ws, size_t ws_size,
                              hipStream_t stream){
  const float* x  = (const float*)d_in[0];
  const float* Wq = (const float*)d_in[1];
  const float* bq = (const float*)d_in[2];
  const float* Wk = (const float*)d_in[3];
  const float* bk = (const float*)d_in[4];
  const float* Wv = (const float*)d_in[5];
  const float* bv = (const float*)d_in[6];
  const float* Wo = (const float*)d_in[7];
  const float* bo = (const float*)d_in[8];
  const float* scale = (const float*)d_in[9];
  float* out = (float*)d_out;

  char* ws = (char*)d_ws;
  const size_t MB = 1024*1024;
  unsigned short* xh  = (unsigned short*)(ws + 0*MB);    // 8 MB
  unsigned short* wh  = (unsigned short*)(ws + 16*MB);   // 8 MB (Wq,Wk,Wv,Wo bf16)
  unsigned short* Qb  = (unsigned short*)(ws + 32*MB);
  unsigned short* Kb  = (unsigned short*)(ws + 40*MB);
  unsigned short* Vtb = (unsigned short*)(ws + 48*MB);
  unsigned short* Ohi = (unsigned short*)(ws + 56*MB);
  unsigned short* Olo = (unsigned short*)(ws + 64*MB);
  float* bias_cat     = (float*)(ws + 72*MB);

  hipLaunchKernelGGL(k_prep, dim3(2048), dim3(256), 0, stream,
                     x, Wq, Wk, Wv, Wo, bq, bk, bv, xh, wh, bias_cat);
  hipLaunchKernelGGL((k_gemm<128,128,0,0>), dim3(24,32), dim3(256), 0, stream,
                     xh, (const unsigned short*)nullptr, wh, bias_cat, scale,
                     Qb, Kb, Vtb, (float*)nullptr);
  hipLaunchKernelGGL(k_attn, dim3(512), dim3(256), 0, stream, Qb, Kb, Vtb, Ohi, Olo);
  hipLaunchKernelGGL((k_gemm<64,64,1,1>), dim3(16,64), dim3(256), 0, stream,
                     Ohi, Olo, wh + 3u*1048576u, bo, (const float*)nullptr,
                     (unsigned short*)nullptr, (unsigned short*)nullptr,
                     (unsigned short*)nullptr, out);
}